// Round 2
// baseline (134.313 us; speedup 1.0000x reference)
//
#include <hip/hip_runtime.h>

#define NEG_INF (-__builtin_huge_valf())
#define NEG_INF_BITS 0xFF800000

#define CCH   4                 // channels staged per chunk
#define HB    4                 // output h rows per block tile
#define ROWS  (HB + 2)          // 6 (h halo)
#define NROW  (CCH * ROWS)      // 24 rows per buffer
#define BUF   (NROW * 64)       // 1536 floats = 6144 B per buffer
#define SLOTS 6                 // NROW rows * 16 float4 / 64 lanes

// Neighbor fetch via DPP within each 16-lane row (wg axis).
// bound_ctrl=false -> row-boundary lanes take `old` = -inf, which IS the
// W padding at wg==0 (row_shr:1) / wg==15 (row_shl:1). Validated exact in r1.
template <int CTRL>
__device__ __forceinline__ float dpp_neighbor(float v) {
    return __int_as_float(__builtin_amdgcn_update_dpp(
        (int)NEG_INF_BITS, __float_as_int(v), CTRL, 0xF, 0xF, false));
}

// Round-0 skeleton (64-thread blocks, VGPR=56, no spills) + DPP edges +
// global_load_lds double-buffered staging.
// LDS dest for slot k is k*1024 + lane*16 bytes: linear in lane -> matches
// the DMA's wave-uniform-base + lane*16 write pattern exactly.
// Grid (16,8,32) = 4096 waves; LDS 12288 B -> 13 blocks/CU cap.
__global__ __launch_bounds__(64, 4)
void maxplus_conv2d_kernel(const float* __restrict__ x,
                           const float* __restrict__ kern,
                           float* __restrict__ out) {
    __shared__ float xs[2 * BUF];

    const int tid = threadIdx.x;        // 0..63
    const int wg  = tid & 15;
    const int hr  = tid >> 4;           // 0..3
    const int w0  = wg << 2;

    const int h_base = blockIdx.x * HB;
    const int b      = blockIdx.y;
    const int o_base = blockIdx.z << 1; // o pair

    const bool hedge = (h_base == 0) || (h_base == 60);

    // ---- staging slots (chunk-invariant) ----
    const float* xb = x + (size_t)b * (64 * 64 * 64);
    const float* gsrc[SLOTS];
    int          foff[SLOTS];           // float offset in buffer (= k*256 + tid*4)
    bool         vmask[SLOTS];
#pragma unroll
    for (int k = 0; k < SLOTS; ++k) {
        int rowid = k * 4 + hr;         // 0..23, each exactly once per wave
        int cl    = rowid / ROWS;
        int r     = rowid - cl * ROWS;
        int gh    = h_base + r - 1;     // -1..64
        bool v    = (unsigned)gh < 64u;
        gsrc[k]  = xb + ((size_t)cl * 64 + (v ? gh : 0)) * 64 + wg * 4;
        foff[k]  = k * 256 + tid * 4;   // == rowid*64 + w0 (linear-in-lane)
        vmask[k] = v;
    }

    float acc[2][4];
#pragma unroll
    for (int oo = 0; oo < 2; ++oo)
#pragma unroll
        for (int wi = 0; wi < 4; ++wi)
            acc[oo][wi] = NEG_INF;

    // stage chunk 0 into buffer 0 (6 x global_load_lds dwordx4)
#pragma unroll
    for (int k = 0; k < SLOTS; ++k)
        __builtin_amdgcn_global_load_lds(
            (const __attribute__((address_space(1))) void*)gsrc[k],
            (__attribute__((address_space(3))) void*)&xs[k * 256], 16, 0, 0);
    asm volatile("s_waitcnt vmcnt(0)" ::: "memory");
    __syncthreads();

    int cur = 0;
#pragma unroll 1
    for (int cc = 0; cc < 64; cc += CCH) {
        // prefetch next chunk into the other buffer; DMA rides under compute
        if (cc + CCH < 64) {
#pragma unroll
            for (int k = 0; k < SLOTS; ++k) {
                gsrc[k] += CCH * 64 * 64;
                __builtin_amdgcn_global_load_lds(
                    (const __attribute__((address_space(1))) void*)gsrc[k],
                    (__attribute__((address_space(3))) void*)
                        &xs[(cur ^ 1) * BUF + k * 256], 16, 0, 0);
            }
        }

        float* bp = &xs[cur * BUF];

        // h-halo fix: DMA staged clamped garbage into out-of-range rows;
        // overwrite with -inf. Only 2/16 h-blocks enter (wave-uniform skip).
        if (hedge) {
#pragma unroll
            for (int k = 0; k < SLOTS; ++k)
                if (!vmask[k])
                    *(float4*)(bp + foff[k]) =
                        make_float4(NEG_INF, NEG_INF, NEG_INF, NEG_INF);
        }

        // batch tap loads for the whole chunk (wave-uniform -> grouped s_loads)
        float kv[CCH][2][9];
#pragma unroll
        for (int cl = 0; cl < CCH; ++cl)
#pragma unroll
            for (int oo = 0; oo < 2; ++oo) {
                const float* kp = kern + ((size_t)(o_base + oo) * 64 + (cc + cl)) * 9;
#pragma unroll
                for (int t = 0; t < 9; ++t) kv[cl][oo][t] = kp[t];
            }

#pragma unroll
        for (int cl = 0; cl < CCH; ++cl) {
            // x window: 3 rows x [DPP edge | w0..w0+3 b128 | DPP edge]
            float xv[3][6];
#pragma unroll
            for (int r = 0; r < 3; ++r) {
                const int rowid = cl * ROWS + hr + r;
                float4 m = *(const float4*)(bp + rowid * 64 + w0);
                xv[r][0] = dpp_neighbor<0x111>(m.w);  // row_shr:1 -> left edge
                xv[r][1] = m.x; xv[r][2] = m.y; xv[r][3] = m.z; xv[r][4] = m.w;
                xv[r][5] = dpp_neighbor<0x101>(m.x);  // row_shl:1 -> right edge
            }

#pragma unroll
            for (int oo = 0; oo < 2; ++oo) {
                const float* k9 = kv[cl][oo];
#pragma unroll
                for (int wi = 0; wi < 4; ++wi) {
                    float m = acc[oo][wi];
                    // paired -> v_max3_f32: 9 add + 4 max3 + 1 max per out per c
                    float t0 = xv[0][wi + 0] + k9[0];
                    float t1 = xv[0][wi + 1] + k9[1];
                    m = fmaxf(m, fmaxf(t0, t1));
                    t0 = xv[0][wi + 2] + k9[2];
                    t1 = xv[1][wi + 0] + k9[3];
                    m = fmaxf(m, fmaxf(t0, t1));
                    t0 = xv[1][wi + 1] + k9[4];
                    t1 = xv[1][wi + 2] + k9[5];
                    m = fmaxf(m, fmaxf(t0, t1));
                    t0 = xv[2][wi + 0] + k9[6];
                    t1 = xv[2][wi + 1] + k9[7];
                    m = fmaxf(m, fmaxf(t0, t1));
                    m = fmaxf(m, xv[2][wi + 2] + k9[8]);
                    acc[oo][wi] = m;
                }
            }
        }

        // drain this chunk's DMA so the other buffer is ready next iteration
        asm volatile("s_waitcnt vmcnt(0)" ::: "memory");
        __syncthreads();
        cur ^= 1;
    }

    const int h = h_base + hr;
#pragma unroll
    for (int oo = 0; oo < 2; ++oo) {
        float4 v = make_float4(acc[oo][0], acc[oo][1], acc[oo][2], acc[oo][3]);
        *(float4*)(out + ((((size_t)b * 64 + (o_base + oo)) * 64 + h) * 64 + w0)) = v;
    }
}

extern "C" void kernel_launch(void* const* d_in, const int* in_sizes, int n_in,
                              void* d_out, int out_size, void* d_ws, size_t ws_size,
                              hipStream_t stream) {
    const float* x    = (const float*)d_in[0];   // [8,64,64,64]
    const float* kern = (const float*)d_in[1];   // [64,64,3,3]
    float* out = (float*)d_out;                  // [8,64,64,64]

    dim3 grid(16, 8, 32);   // h-tiles, b, o-pairs
    dim3 block(64);
    maxplus_conv2d_kernel<<<grid, block, 0, stream>>>(x, kern, out);
}

// Round 3
// 121.246 us; speedup vs baseline: 1.1078x; 1.1078x over previous
//
#include <hip/hip_runtime.h>

#define NEG_INF (-__builtin_huge_valf())
#define NEG_INF_BITS 0xFF800000

#define CCH   4                 // c's per LDS chunk
#define HB    4                 // output h rows per wave tile
#define ROWS  (HB + 2)          // 6 (h halo)
#define NROW  (CCH * ROWS)      // 24 staged rows
#define XSTR  64                // xs row stride (floats): pure data, no edge array
#define SLOTS 6                 // NROW*16 float4 / 64 lanes

// Neighbor fetch via DPP within each 16-lane row (wg axis).
// bound_ctrl=false -> row-boundary lanes take `old` = -inf, which IS the
// W padding at wg==0 (row_shr:1) / wg==15 (row_shl:1). Validated exact r1/r2.
template <int CTRL>
__device__ __forceinline__ float dpp_neighbor(float v) {
    return __int_as_float(__builtin_amdgcn_update_dpp(
        (int)NEG_INF_BITS, __float_as_int(v), CTRL, 0xF, 0xF, false));
}

// 9-tap max-plus update: 9 add + 4 max3 + 1 max per output per channel.
__device__ __forceinline__ void maxplus9(const float xv[3][6], const float* k9,
                                         float a[4]) {
#pragma unroll
    for (int wi = 0; wi < 4; ++wi) {
        float m = a[wi];
        float t0 = xv[0][wi + 0] + k9[0];
        float t1 = xv[0][wi + 1] + k9[1];
        m = fmaxf(m, fmaxf(t0, t1));
        t0 = xv[0][wi + 2] + k9[2];
        t1 = xv[1][wi + 0] + k9[3];
        m = fmaxf(m, fmaxf(t0, t1));
        t0 = xv[1][wi + 1] + k9[4];
        t1 = xv[1][wi + 2] + k9[5];
        m = fmaxf(m, fmaxf(t0, t1));
        t0 = xv[2][wi + 0] + k9[6];
        t1 = xv[2][wi + 1] + k9[7];
        m = fmaxf(m, fmaxf(t0, t1));
        m = fmaxf(m, xv[2][wi + 2] + k9[8]);
        a[wi] = m;
    }
}

// r0 skeleton (64-thr blocks, reg-prefetch + ds_write staging, 2 barriers)
// + DPP edges (es array deleted, LDS 10240->6144)
// + o-QUAD per wave: grid z 32->16 => 2048 blocks = exactly 8 blocks/CU,
//   matching the ~8.6 blocks/CU residency measured in r0. Staging+barrier
//   cost amortized over 4 output channels; 2x compute per LDS read region.
__global__ __launch_bounds__(64, 2)
void maxplus_conv2d_kernel(const float* __restrict__ x,
                           const float* __restrict__ kern,
                           float* __restrict__ out) {
    __shared__ float xs[NROW * XSTR];   // 6144 B

    const int tid = threadIdx.x;        // 0..63
    const int wg  = tid & 15;
    const int hr  = tid >> 4;           // 0..3
    const int w0  = wg << 2;

    const int h_base = blockIdx.x * HB;
    const int b      = blockIdx.y;
    const int o_base = blockIdx.z << 2; // o quad

    // ---- staging slots (chunk-invariant) ----
    const float* xb = x + (size_t)b * (64 * 64 * 64);
    const float* gsrc[SLOTS];
    float*       xdst[SLOTS];
    bool         vmask[SLOTS];
#pragma unroll
    for (int k = 0; k < SLOTS; ++k) {
        int rowid = k * 4 + hr;           // 0..23, each exactly once per wave
        int cl    = rowid / ROWS;
        int r     = rowid - cl * ROWS;
        int gh    = h_base + r - 1;       // -1..64
        bool v    = (unsigned)gh < 64u;
        gsrc[k]  = xb + ((size_t)cl * 64 + (v ? gh : 0)) * 64 + wg * 4;
        xdst[k]  = &xs[rowid * XSTR + wg * 4];   // aligned ds_write_b128
        vmask[k] = v;
    }

    float acc[4][4];
#pragma unroll
    for (int oo = 0; oo < 4; ++oo)
#pragma unroll
        for (int wi = 0; wi < 4; ++wi)
            acc[oo][wi] = NEG_INF;

    // prefetch chunk 0 into registers
    float4 R[SLOTS];
#pragma unroll
    for (int k = 0; k < SLOTS; ++k) R[k] = *(const float4*)gsrc[k];

#pragma unroll 1
    for (int cc = 0; cc < 64; cc += CCH) {
        __syncthreads();   // WAR: prev chunk's reads before these writes

#pragma unroll
        for (int k = 0; k < SLOTS; ++k) {
            float4 v = R[k];
            if (!vmask[k]) v = make_float4(NEG_INF, NEG_INF, NEG_INF, NEG_INF);
            *(float4*)xdst[k] = v;
        }

        __syncthreads();   // RAW: writes visible before cross-lane reads

        if (cc + CCH < 64) {   // prefetch next chunk; vmcnt rides under compute
#pragma unroll
            for (int k = 0; k < SLOTS; ++k) {
                gsrc[k] += CCH * 64 * 64;
                R[k] = *(const float4*)gsrc[k];
            }
        }

        // two o-pairs consume the SAME staged x chunk (full unroll: all acc
        // indices static; kv live range = 72 scalars per o-pair, SGPR-safe)
#pragma unroll
        for (int op = 0; op < 2; ++op) {
            // batch tap loads for this o-pair (wave-uniform -> grouped s_loads)
            float kv[CCH][2][9];
#pragma unroll
            for (int cl = 0; cl < CCH; ++cl)
#pragma unroll
                for (int oo = 0; oo < 2; ++oo) {
                    const float* kp =
                        kern + ((size_t)(o_base + op * 2 + oo) * 64 + (cc + cl)) * 9;
#pragma unroll
                    for (int t = 0; t < 9; ++t) kv[cl][oo][t] = kp[t];
                }

#pragma unroll
            for (int cl = 0; cl < CCH; ++cl) {
                // x window: 3 rows x [DPP edge | w0..w0+3 b128 | DPP edge]
                float xv[3][6];
#pragma unroll
                for (int r = 0; r < 3; ++r) {
                    const int rowid = cl * ROWS + hr + r;
                    float4 m = *(const float4*)(&xs[rowid * XSTR + w0]);
                    xv[r][0] = dpp_neighbor<0x111>(m.w);  // row_shr:1 -> left edge
                    xv[r][1] = m.x; xv[r][2] = m.y; xv[r][3] = m.z; xv[r][4] = m.w;
                    xv[r][5] = dpp_neighbor<0x101>(m.x);  // row_shl:1 -> right edge
                }
                maxplus9(xv, kv[cl][0], acc[op * 2 + 0]);
                maxplus9(xv, kv[cl][1], acc[op * 2 + 1]);
            }
        }
    }

    const int h = h_base + hr;
#pragma unroll
    for (int oo = 0; oo < 4; ++oo) {
        float4 v = make_float4(acc[oo][0], acc[oo][1], acc[oo][2], acc[oo][3]);
        *(float4*)(out + ((((size_t)b * 64 + (o_base + oo)) * 64 + h) * 64 + w0)) = v;
    }
}

extern "C" void kernel_launch(void* const* d_in, const int* in_sizes, int n_in,
                              void* d_out, int out_size, void* d_ws, size_t ws_size,
                              hipStream_t stream) {
    const float* x    = (const float*)d_in[0];   // [8,64,64,64]
    const float* kern = (const float*)d_in[1];   // [64,64,3,3]
    float* out = (float*)d_out;                  // [8,64,64,64]

    dim3 grid(16, 8, 16);   // h-tiles, b, o-quads
    dim3 block(64);
    maxplus_conv2d_kernel<<<grid, block, 0, stream>>>(x, kern, out);
}

// Round 4
// 121.052 us; speedup vs baseline: 1.1095x; 1.0016x over previous
//
#include <hip/hip_runtime.h>

#define NEG_INF (-__builtin_huge_valf())
#define NEG_INF_BITS 0xFF800000

// Neighbor fetch via DPP within each 16-lane row (wg axis).
// bound_ctrl=false -> row-boundary lanes take `old` = -inf, which IS the
// W padding at wg==0 (row_shr:1) / wg==15 (row_shl:1). Validated exact r1-r3.
template <int CTRL>
__device__ __forceinline__ float dpp_neighbor(float v) {
    return __int_as_float(__builtin_amdgcn_update_dpp(
        (int)NEG_INF_BITS, __float_as_int(v), CTRL, 0xF, 0xF, false));
}

// 9-tap max-plus update: 9 add + 4 max3 + 1 max per output per channel.
__device__ __forceinline__ void maxplus9(const float xv[3][6], const float* k9,
                                         float a[4]) {
#pragma unroll
    for (int wi = 0; wi < 4; ++wi) {
        float m = a[wi];
        float t0 = xv[0][wi + 0] + k9[0];
        float t1 = xv[0][wi + 1] + k9[1];
        m = fmaxf(m, fmaxf(t0, t1));
        t0 = xv[0][wi + 2] + k9[2];
        t1 = xv[1][wi + 0] + k9[3];
        m = fmaxf(m, fmaxf(t0, t1));
        t0 = xv[1][wi + 1] + k9[4];
        t1 = xv[1][wi + 2] + k9[5];
        m = fmaxf(m, fmaxf(t0, t1));
        t0 = xv[2][wi + 0] + k9[6];
        t1 = xv[2][wi + 1] + k9[7];
        m = fmaxf(m, fmaxf(t0, t1));
        m = fmaxf(m, xv[2][wi + 2] + k9[8]);
        a[wi] = m;
    }
}

// Direct-global version: NO LDS, NO barriers. Each lane loads its 3 rows
// (float4) straight from global per channel — for fixed r the wave's 64
// addresses span 4 consecutive image rows = 1 KB contiguous (perfectly
// coalesced), and rows overlap across the three loads -> 2/3 are L1 hits.
// x block slice is tiny and L2-resident; redundancy never reaches HBM.
// Grid (16,8,32) = 4096 single-wave blocks = 4 waves/SIMD (the r0-proven
// residency shape), now with zero serialization points per chunk.
__global__ __launch_bounds__(64, 4)
void maxplus_conv2d_kernel(const float* __restrict__ x,
                           const float* __restrict__ kern,
                           float* __restrict__ out) {
    const int tid = threadIdx.x;        // 0..63
    const int wg  = tid & 15;
    const int hr  = tid >> 4;           // 0..3
    const int w0  = wg << 2;

    const int h_base = blockIdx.x * 4;
    const int b      = blockIdx.y;
    const int o_base = blockIdx.z << 1; // o pair

    const float* xb = x + (size_t)b * (64 * 64 * 64);

    // Per-lane 32-bit float-offsets from xb (SGPR base + VGPR offset form).
    // Row r of the window is image row gh = h_base + hr - 1 + r.
    // r=1 is always in range; r=0 (top, hr==0 @ h_base==0) and r=2
    // (bottom, hr==3 @ h_base==60) can fall outside -> clamped address,
    // value replaced by -inf via hoisted-mask cndmask.
    int  off[3];
    bool rv[3];
#pragma unroll
    for (int r = 0; r < 3; ++r) {
        int gh = h_base + hr - 1 + r;
        rv[r]  = (unsigned)gh < 64u;
        off[r] = (rv[r] ? gh : 0) * 64 + w0;
    }

    float acc[2][4];
#pragma unroll
    for (int oo = 0; oo < 2; ++oo)
#pragma unroll
        for (int wi = 0; wi < 4; ++wi)
            acc[oo][wi] = NEG_INF;

    const float* kp0 = kern + (size_t)(o_base + 0) * (64 * 9);
    const float* kp1 = kern + (size_t)(o_base + 1) * (64 * 9);

#pragma unroll 1
    for (int cc = 0; cc < 64; cc += 4) {
        // scalar taps for this 4-channel group (wave-uniform -> s_loads)
        float kv[4][2][9];
#pragma unroll
        for (int cl = 0; cl < 4; ++cl)
#pragma unroll
            for (int t = 0; t < 9; ++t) {
                kv[cl][0][t] = kp0[(cc + cl) * 9 + t];
                kv[cl][1][t] = kp1[(cc + cl) * 9 + t];
            }

        // issue all 12 row loads for the group back-to-back (VMEM pipelines)
        float4 mm[4][3];
#pragma unroll
        for (int cl = 0; cl < 4; ++cl)
#pragma unroll
            for (int r = 0; r < 3; ++r)
                mm[cl][r] = *(const float4*)(xb + ((cc + cl) * 4096 + off[r]));

        // compute
#pragma unroll
        for (int cl = 0; cl < 4; ++cl) {
            float xv[3][6];
#pragma unroll
            for (int r = 0; r < 3; ++r) {
                float4 m = mm[cl][r];
                if (r != 1 && !rv[r])   // mask hoisted to SGPR pair; 4 cndmask
                    m = make_float4(NEG_INF, NEG_INF, NEG_INF, NEG_INF);
                xv[r][0] = dpp_neighbor<0x111>(m.w);  // row_shr:1 -> left edge
                xv[r][1] = m.x; xv[r][2] = m.y; xv[r][3] = m.z; xv[r][4] = m.w;
                xv[r][5] = dpp_neighbor<0x101>(m.x);  // row_shl:1 -> right edge
            }
            maxplus9(xv, kv[cl][0], acc[0]);
            maxplus9(xv, kv[cl][1], acc[1]);
        }
    }

    const int h = h_base + hr;
#pragma unroll
    for (int oo = 0; oo < 2; ++oo) {
        float4 v = make_float4(acc[oo][0], acc[oo][1], acc[oo][2], acc[oo][3]);
        *(float4*)(out + ((((size_t)b * 64 + (o_base + oo)) * 64 + h) * 64 + w0)) = v;
    }
}

extern "C" void kernel_launch(void* const* d_in, const int* in_sizes, int n_in,
                              void* d_out, int out_size, void* d_ws, size_t ws_size,
                              hipStream_t stream) {
    const float* x    = (const float*)d_in[0];   // [8,64,64,64]
    const float* kern = (const float*)d_in[1];   // [64,64,3,3]
    float* out = (float*)d_out;                  // [8,64,64,64]

    dim3 grid(16, 8, 32);   // h-tiles, b, o-pairs
    dim3 block(64);
    maxplus_conv2d_kernel<<<grid, block, 0, stream>>>(x, kern, out);
}